// Round 1
// baseline (152.026 us; speedup 1.0000x reference)
//
#include <hip/hip_runtime.h>
#include <math.h>

// VQC_Registers_BS_density: 16 layers of U rho U^T with U_l = G(th_l) (x) I
// (even l, row-register pairs) or I (x) G(th_l) (odd l, col-register pairs).
// G's 2x2 blocks M(th)=[[sin,cos],[-cos,sin]]=R(th-pi/2) are rotations on the
// SAME pair structure every layer with a scalar angle per layer, so the whole
// product collapses exactly to (R(SA) (x) R(SB)) rho (R(SA) (x) R(SB))^T with
// SA = sum of even-layer angles, SB = sum of odd-layer angles
// (8 factors of -pi/2 = -4pi = identity).
//
// Flat index of rho[s,t], s=r1*32+c1, t=r2*32+c2:
//   idx = r1*32768 + c1*1024 + r2*32 + c2
// The transform is 4 independent 2-point butterflies along the low bit of each
// of r1 (stride 32768), c1 (1024), r2 (32), c2 (1). Each 16-element group is
// closed: one thread per group, 65536 threads total.

__global__ __launch_bounds__(256) void vqc_bs_density_kernel(
    const float* __restrict__ rho,
    const float* __restrict__ angles,
    float* __restrict__ out) {

    // Composed angles (wave-uniform; angles array is 64 B, L1-resident).
    float SA = 0.f, SB = 0.f;
#pragma unroll
    for (int l = 0; l < 16; l += 2) SA += angles[l];
#pragma unroll
    for (int l = 1; l < 16; l += 2) SB += angles[l];
    float ca, sa, cb, sb;
    sincosf(SA, &sa, &ca);
    sincosf(SB, &sb, &cb);

    const int gid = blockIdx.x * blockDim.x + threadIdx.x;  // 0..65535
    const int c2g = gid & 15;
    const int r2g = (gid >> 4) & 15;
    const int c1g = (gid >> 8) & 15;
    const int r1g = (gid >> 12) & 15;

    // Base element: all four low bits = 0.
    const int base = ((r1g * 2) * 32 + (c1g * 2)) * 1024 + (r2g * 2) * 32 + (c2g * 2);

    // v[dr1][dc1][dr2][dc2]
    float v[2][2][2][2];
#pragma unroll
    for (int dr1 = 0; dr1 < 2; ++dr1)
#pragma unroll
        for (int dc1 = 0; dc1 < 2; ++dc1)
#pragma unroll
            for (int dr2 = 0; dr2 < 2; ++dr2) {
                const float2 t = *(const float2*)(rho + base + dr1 * 32768 + dc1 * 1024 + dr2 * 32);
                v[dr1][dc1][dr2][0] = t.x;
                v[dr1][dc1][dr2][1] = t.y;
            }

    // Stage r1: block [[ca,-sa],[sa,ca]] on (even,odd) along dr1.
#pragma unroll
    for (int dc1 = 0; dc1 < 2; ++dc1)
#pragma unroll
        for (int dr2 = 0; dr2 < 2; ++dr2)
#pragma unroll
            for (int dc2 = 0; dc2 < 2; ++dc2) {
                const float e = v[0][dc1][dr2][dc2];
                const float o = v[1][dc1][dr2][dc2];
                v[0][dc1][dr2][dc2] = ca * e - sa * o;
                v[1][dc1][dr2][dc2] = sa * e + ca * o;
            }

    // Stage c1: (cb,sb) along dc1.
#pragma unroll
    for (int dr1 = 0; dr1 < 2; ++dr1)
#pragma unroll
        for (int dr2 = 0; dr2 < 2; ++dr2)
#pragma unroll
            for (int dc2 = 0; dc2 < 2; ++dc2) {
                const float e = v[dr1][0][dr2][dc2];
                const float o = v[dr1][1][dr2][dc2];
                v[dr1][0][dr2][dc2] = cb * e - sb * o;
                v[dr1][1][dr2][dc2] = sb * e + cb * o;
            }

    // Stage r2: (ca,sa) along dr2.
#pragma unroll
    for (int dr1 = 0; dr1 < 2; ++dr1)
#pragma unroll
        for (int dc1 = 0; dc1 < 2; ++dc1)
#pragma unroll
            for (int dc2 = 0; dc2 < 2; ++dc2) {
                const float e = v[dr1][dc1][0][dc2];
                const float o = v[dr1][dc1][1][dc2];
                v[dr1][dc1][0][dc2] = ca * e - sa * o;
                v[dr1][dc1][1][dc2] = sa * e + ca * o;
            }

    // Stage c2: (cb,sb) along dc2.
#pragma unroll
    for (int dr1 = 0; dr1 < 2; ++dr1)
#pragma unroll
        for (int dc1 = 0; dc1 < 2; ++dc1)
#pragma unroll
            for (int dr2 = 0; dr2 < 2; ++dr2) {
                const float e = v[dr1][dc1][dr2][0];
                const float o = v[dr1][dc1][dr2][1];
                v[dr1][dc1][dr2][0] = cb * e - sb * o;
                v[dr1][dc1][dr2][1] = sb * e + cb * o;
            }

    // Store (same pattern as load, to the separate output buffer).
#pragma unroll
    for (int dr1 = 0; dr1 < 2; ++dr1)
#pragma unroll
        for (int dc1 = 0; dc1 < 2; ++dc1)
#pragma unroll
            for (int dr2 = 0; dr2 < 2; ++dr2) {
                float2 t;
                t.x = v[dr1][dc1][dr2][0];
                t.y = v[dr1][dc1][dr2][1];
                *(float2*)(out + base + dr1 * 32768 + dc1 * 1024 + dr2 * 32) = t;
            }
}

extern "C" void kernel_launch(void* const* d_in, const int* in_sizes, int n_in,
                              void* d_out, int out_size, void* d_ws, size_t ws_size,
                              hipStream_t stream) {
    const float* rho = (const float*)d_in[0];     // input_state, 1024*1024 f32
    const float* angles = (const float*)d_in[1];  // 16 f32
    float* out = (float*)d_out;                   // 1024*1024 f32
    // 65536 groups of 16 elements; 256 blocks x 256 threads.
    vqc_bs_density_kernel<<<256, 256, 0, stream>>>(rho, angles, out);
}